// Round 11
// baseline (175.057 us; speedup 1.0000x reference)
//
#include <hip/hip_runtime.h>

#define D 64
#define EPS 2.5e-4f      // >= 3x the fp16-split worst-case score-error bound
#define KSPLIT 2
#define CHUNK 64         // centroids per LDS tile
#define INVSC 4.8828125e-4f   // 2^-11, exact

typedef __attribute__((ext_vector_type(8))) _Float16 f16x8;
typedef __attribute__((ext_vector_type(4))) float f32x4;

// async global->LDS, 16 B per lane. LDS dst = wave-uniform base + lane*16.
static __device__ __forceinline__ void async16(const void* g, void* l) {
    __builtin_amdgcn_global_load_lds(
        (const __attribute__((address_space(1))) unsigned int*)((unsigned long long)g),
        (__attribute__((address_space(3))) unsigned int*)((unsigned int)(unsigned long long)l),
        16, 0, 0);
}

// prep: pre-swizzled fp16 hi/lo centroid images + c2 + zero counter.
// hi = fp16(c); lo = fp16((c - hi) * 2^11)  (scaling keeps lo normal-range).
// Image: per 64-centroid chunk (8192 B), frag for centroid k=(kc*16+col),
// d-octet (ks*32+quad*8) at ((kc*2+ks)*64 + quad*16 + col)*16 B, so a flat
// lane-contiguous LDS copy puts lane (quad*16+col)'s MFMA B-frag at lane*16.
__global__ void prep_kernel(const float* __restrict__ c, _Float16* __restrict__ chs,
                            _Float16* __restrict__ cls, float* __restrict__ c2,
                            int K, int* __restrict__ counter) {
    int t = blockIdx.x * blockDim.x + threadIdx.x;
    if (t == 0) *counter = 0;
    const int nfr = K * 8;
    if (t < nfr) {
        const int k = t >> 3, f = t & 7;
        const int ks = f >> 2, quad = f & 3;
        const int chunk = k >> 6, kc = (k >> 4) & 3, col = k & 15;
        const size_t off = (size_t)chunk * 4096 +
                           (size_t)(((kc * 2 + ks) * 64 + quad * 16 + col) * 8);
        const float* src = c + (size_t)k * D + f * 8;
        f16x8 h, l;
#pragma unroll
        for (int j = 0; j < 8; ++j) {
            float x = src[j];
            _Float16 hs = (_Float16)x;
            h[j] = hs;
            l[j] = (_Float16)((x - (float)hs) * 2048.f);
        }
        *(f16x8*)(chs + off) = h;
        *(f16x8*)(cls + off) = l;
    }
    if (t < K) {
        const float4* cp = (const float4*)(c + (size_t)t * D);
        float s = 0.f;
#pragma unroll
        for (int i = 0; i < D / 4; ++i) {
            float4 v = cp[i];
            s += v.x * v.x; s += v.y * v.y; s += v.z * v.z; s += v.w * v.w;
        }
        c2[t] = s;
    }
}

// Pass 1: fp16-hi/lo MFMA scan, B via double-buffered async LDS.
// a' = -2a (exact). score = c2[k] + a'.c, with
//   acc1 (init c2) += ah.ch ;  acc2 (x2^11) += ah.cl' + al'.ch
//   s = acc1 + 2^-11 * acc2
// kc processed in wave-staggered order (kc = kcs ^ wv) to de-phase the four
// waves' LDS/MFMA/VALU bursts (barrier phase-lock made pipes serialize in
// r10). Order-safety: unique-min-by-EPS => order irrelevant; near-ties are
// flagged and exactly rescanned.
__global__ __launch_bounds__(256, 4) void pass1_kernel(
    const float* __restrict__ action, const _Float16* __restrict__ chs,
    const _Float16* __restrict__ cls, const float* __restrict__ c2,
    float4* __restrict__ cand, int N, int K) {
    __shared__ _Float16 ldsbuf[2][2][4096];   // [dbuf][hi/lo][8 KB] = 32 KB

    const int tid  = threadIdx.x;
    const int wv   = tid >> 6;
    const int lane = tid & 63;
    const int col  = lane & 15;
    const int quad = lane >> 4;
    const int m0   = blockIdx.x * 128 + wv * 32;
    const int KC   = K / KSPLIT;
    const int k0   = blockIdx.y * KC;
    const int NC   = KC / CHUNK;           // 16
    const int ch0  = k0 >> 6;              // first chunk id

#define STAGE(cid_, buf_)                                                     \
    {                                                                         \
        const size_t gb = (size_t)(cid_) * 4096;                              \
        _Pragma("unroll") for (int r = 0; r < 2; ++r) {                       \
            const int el = (r * 256 + tid) * 8;                               \
            const int lb = (r * 256 + wv * 64) * 8;                           \
            async16(chs + gb + el, &ldsbuf[buf_][0][lb]);                     \
            async16(cls + gb + el, &ldsbuf[buf_][1][lb]);                     \
        }                                                                     \
    }

    STAGE(ch0, 0)   // chunk 0 in flight under A-fragment conversion

    // A fragments: a' = -2a -> fp16 hi + scaled fp16 lo, in registers once.
    f16x8 ah[2][2], al[2][2];
#pragma unroll
    for (int mi = 0; mi < 2; ++mi) {
        const float* arow = action + (size_t)(m0 + mi * 16 + col) * D;
#pragma unroll
        for (int ks = 0; ks < 2; ++ks) {
            const float* src = arow + ks * 32 + quad * 8;
            f16x8 h, l;
#pragma unroll
            for (int j = 0; j < 8; ++j) {
                float x = -2.f * src[j];
                _Float16 hs = (_Float16)x;
                h[j] = hs;
                l[j] = (_Float16)((x - (float)hs) * 2048.f);
            }
            ah[mi][ks] = h;
            al[mi][ks] = l;
        }
    }

    float b1[8], b2[8];
    int   bk[8];
#pragma unroll
    for (int e = 0; e < 8; ++e) {
        b1[e] = __builtin_inff(); b2[e] = __builtin_inff(); bk[e] = k0;
    }

#define FOLD(kk_)                                                             \
    _Pragma("unroll") for (int r = 0; r < 4; ++r) {                           \
        const int e = mi * 4 + r;                                             \
        const float s = fmaf(INVSC, acc2[r], acc1[r]);                        \
        b2[e] = __builtin_amdgcn_fmed3f(s, b1[e], b2[e]);                     \
        const bool better = s < b1[e];                                        \
        b1[e] = fminf(b1[e], s);                                              \
        bk[e] = better ? (kk_) : bk[e];                                       \
    }

#define KCBODY(kc_, cc_)                                                      \
    {                                                                         \
        f16x8 bh0 = *(const f16x8*)&ldsbuf[buf][0][(((kc_)*2+0)*64+lane)*8];  \
        f16x8 bh1 = *(const f16x8*)&ldsbuf[buf][0][(((kc_)*2+1)*64+lane)*8];  \
        f16x8 bl0 = *(const f16x8*)&ldsbuf[buf][1][(((kc_)*2+0)*64+lane)*8];  \
        f16x8 bl1 = *(const f16x8*)&ldsbuf[buf][1][(((kc_)*2+1)*64+lane)*8];  \
        const int k = kbase + (kc_)*16 + col;                                 \
        _Pragma("unroll") for (int mi = 0; mi < 2; ++mi) {                    \
            f32x4 acc1 = {cc_, cc_, cc_, cc_};                                \
            f32x4 acc2 = {0.f, 0.f, 0.f, 0.f};                                \
            acc2 = __builtin_amdgcn_mfma_f32_16x16x32_f16(al[mi][0], bh0, acc2, 0, 0, 0); \
            acc2 = __builtin_amdgcn_mfma_f32_16x16x32_f16(ah[mi][0], bl0, acc2, 0, 0, 0); \
            acc1 = __builtin_amdgcn_mfma_f32_16x16x32_f16(ah[mi][0], bh0, acc1, 0, 0, 0); \
            acc2 = __builtin_amdgcn_mfma_f32_16x16x32_f16(al[mi][1], bh1, acc2, 0, 0, 0); \
            acc2 = __builtin_amdgcn_mfma_f32_16x16x32_f16(ah[mi][1], bl1, acc2, 0, 0, 0); \
            acc1 = __builtin_amdgcn_mfma_f32_16x16x32_f16(ah[mi][1], bh1, acc1, 0, 0, 0); \
            FOLD(k)                                                           \
        }                                                                     \
    }

    for (int c = 0; c < NC; ++c) {
        const int buf = c & 1;
        __syncthreads();                    // chunk c resident in ldsbuf[buf]
        const int kbase = k0 + c * CHUNK;
        const float cc0 = c2[kbase + ((0 ^ wv) * 16) + col];
        const float cc1 = c2[kbase + ((1 ^ wv) * 16) + col];
        const float cc2 = c2[kbase + ((2 ^ wv) * 16) + col];
        const float cc3 = c2[kbase + ((3 ^ wv) * 16) + col];
        if (c + 1 < NC) STAGE(ch0 + c + 1, buf ^ 1)   // in flight under compute
        KCBODY((0 ^ wv), cc0)
        KCBODY((1 ^ wv), cc1)
        KCBODY((2 ^ wv), cc2)
        KCBODY((3 ^ wv), cc3)
    }
#undef KCBODY
#undef FOLD
#undef STAGE

    // cross-lane top-2 merge over the 16 centroid columns
#pragma unroll
    for (int off = 1; off < 16; off <<= 1) {
#pragma unroll
        for (int e = 0; e < 8; ++e) {
            float o1 = __shfl_xor(b1[e], off, 64);
            float o2 = __shfl_xor(b2[e], off, 64);
            int   ok = __shfl_xor(bk[e], off, 64);
            bool take = (o1 < b1[e]) || (o1 == b1[e] && ok < bk[e]);
            float nb2 = take ? fminf(b1[e], o2) : fminf(b2[e], o1);
            b1[e] = take ? o1 : b1[e];
            bk[e] = take ? ok : bk[e];
            b2[e] = nb2;
        }
    }

    if (col == 0) {
#pragma unroll
        for (int e = 0; e < 8; ++e) {
            const int mi = e >> 2, r = e & 3;
            const int p = m0 + mi * 16 + quad * 4 + r;
            cand[(size_t)blockIdx.y * N + p] =
                make_float4(b1[e], b2[e], (float)bk[e], 0.f);
        }
    }
}

// Fused merge + bin write + ambiguity flag + exact fp32 residual.
__global__ __launch_bounds__(256) void resflag_kernel(
    const float* __restrict__ action, const float* __restrict__ centroids,
    const float4* __restrict__ cand, float* __restrict__ out_bin,
    float* __restrict__ out_res, int* __restrict__ counter,
    int* __restrict__ flags, int N) {
    int n = blockIdx.x * blockDim.x + threadIdx.x;
    if (n >= N) return;
    float4 v0 = cand[n];
    float4 v1 = cand[(size_t)N + n];
    float b1, b2; int bk;
    if (v1.x < v0.x) { b1 = v1.x; bk = (int)v1.z; b2 = fminf(v0.x, v1.y); }
    else             { b1 = v0.x; bk = (int)v0.z; b2 = fminf(v1.x, v0.y); }
    out_bin[n] = (float)bk;
    if (b2 - b1 < EPS) {
        int idx = atomicAdd(counter, 1);
        flags[idx] = n;
    }
    const float4* ap = (const float4*)(action + (size_t)n * D);
    const float4* cp = (const float4*)(centroids + (size_t)bk * D);
    float4*       rp = (float4*)(out_res + (size_t)n * D);
#pragma unroll
    for (int i = 0; i < D / 4; ++i) {
        float4 a = ap[i], c = cp[i];
        rp[i] = make_float4(a.x - c.x, a.y - c.y, a.z - c.z, a.w - c.w);
    }
}

// Exact fp32 rescan for flagged points. Block-per-point grid-stride,
// 4 interleaved dot accumulators for ILP. numpy first-min tie-break.
__global__ __launch_bounds__(256) void exact_kernel(
    const float* __restrict__ action, const float* __restrict__ centroids,
    const float* __restrict__ c2, const int* __restrict__ counter,
    const int* __restrict__ flags, float* __restrict__ out_bin,
    float* __restrict__ out_res, int K) {
    __shared__ float4 sa[D / 4];
    __shared__ float  swv[4];
    __shared__ int    swk[4];
    __shared__ int    s_bk;
    const int count = *counter;
    const int tid = threadIdx.x, lane = tid & 63, wid = tid >> 6;
    for (int i = blockIdx.x; i < count; i += gridDim.x) {
        const int n = flags[i];
        __syncthreads();
        if (tid < D / 4) sa[tid] = ((const float4*)(action + (size_t)n * D))[tid];
        __syncthreads();
        float best = __builtin_inff();
        int bbk = 0x7fffffff;
        for (int k = tid; k < K; k += 256) {
            const float4* cr = (const float4*)(centroids + (size_t)k * D);
            float d0 = 0.f, d1 = 0.f, d2 = 0.f, d3 = 0.f;
#pragma unroll
            for (int q = 0; q < 4; ++q) {
                float4 a0 = sa[q * 4 + 0], c0 = cr[q * 4 + 0];
                float4 a1 = sa[q * 4 + 1], c1 = cr[q * 4 + 1];
                float4 a2 = sa[q * 4 + 2], c2v = cr[q * 4 + 2];
                float4 a3 = sa[q * 4 + 3], c3 = cr[q * 4 + 3];
                d0 = fmaf(a0.x, c0.x, d0); d0 = fmaf(a0.y, c0.y, d0);
                d0 = fmaf(a0.z, c0.z, d0); d0 = fmaf(a0.w, c0.w, d0);
                d1 = fmaf(a1.x, c1.x, d1); d1 = fmaf(a1.y, c1.y, d1);
                d1 = fmaf(a1.z, c1.z, d1); d1 = fmaf(a1.w, c1.w, d1);
                d2 = fmaf(a2.x, c2v.x, d2); d2 = fmaf(a2.y, c2v.y, d2);
                d2 = fmaf(a2.z, c2v.z, d2); d2 = fmaf(a2.w, c2v.w, d2);
                d3 = fmaf(a3.x, c3.x, d3); d3 = fmaf(a3.y, c3.y, d3);
                d3 = fmaf(a3.z, c3.z, d3); d3 = fmaf(a3.w, c3.w, d3);
            }
            float dot = (d0 + d1) + (d2 + d3);
            float s = fmaf(-2.f, dot, c2[k]);
            if (s < best) { best = s; bbk = k; }  // ascending k: first-min
        }
#pragma unroll
        for (int off = 32; off > 0; off >>= 1) {
            float ov = __shfl_down(best, off, 64);
            int   ok = __shfl_down(bbk, off, 64);
            if (ov < best || (ov == best && ok < bbk)) { best = ov; bbk = ok; }
        }
        if (lane == 0) { swv[wid] = best; swk[wid] = bbk; }
        __syncthreads();
        if (tid == 0) {
            float bb = swv[0]; int bki = swk[0];
#pragma unroll
            for (int t = 1; t < 4; ++t)
                if (swv[t] < bb || (swv[t] == bb && swk[t] < bki)) {
                    bb = swv[t]; bki = swk[t];
                }
            out_bin[n] = (float)bki;
            s_bk = bki;
        }
        __syncthreads();
        if (tid < D / 4) {
            float4 a = sa[tid];
            float4 c = ((const float4*)(centroids + (size_t)s_bk * D))[tid];
            ((float4*)(out_res + (size_t)n * D))[tid] =
                make_float4(a.x - c.x, a.y - c.y, a.z - c.z, a.w - c.w);
        }
    }
}

extern "C" void kernel_launch(void* const* d_in, const int* in_sizes, int n_in,
                              void* d_out, int out_size, void* d_ws, size_t ws_size,
                              hipStream_t stream) {
    const float* action    = (const float*)d_in[0];  // [N, 64]
    const float* centroids = (const float*)d_in[1];  // [K, 64]
    const int N = in_sizes[0] / D;  // 65536
    const int K = in_sizes[1] / D;  // 2048

    float* out_bin = (float*)d_out;      // N floats: argmin index
    float* out_res = (float*)d_out + N;  // N*D residuals

    // ws layout (~2.9 MB)
    char* w = (char*)d_ws;
    float*     c2      = (float*)w;                       // 8 KB
    int*       counter = (int*)(w + 8192);                // 4 B (padded to 256)
    int*       flags   = (int*)(w + 8448);                // N*4 = 256 KB
    _Float16*  chs     = (_Float16*)(w + 8448 + 262144);  // K*D*2 = 256 KB (swizzled)
    _Float16*  cls     = chs + (size_t)K * D;             // 256 KB (swizzled)
    float4*    cand    = (float4*)(cls + (size_t)K * D);  // KSPLIT*N*16 = 2 MB

    prep_kernel<<<(K * 8 + 255) / 256, 256, 0, stream>>>(centroids, chs, cls,
                                                         c2, K, counter);
    dim3 g1(N / 128, KSPLIT);
    pass1_kernel<<<g1, 256, 0, stream>>>(action, chs, cls, c2, cand, N, K);
    resflag_kernel<<<(N + 255) / 256, 256, 0, stream>>>(action, centroids, cand,
                                                        out_bin, out_res, counter,
                                                        flags, N);
    exact_kernel<<<2048, 256, 0, stream>>>(action, centroids, c2, counter, flags,
                                           out_bin, out_res, K);
}

// Round 12
// 157.678 us; speedup vs baseline: 1.1102x; 1.1102x over previous
//
#include <hip/hip_runtime.h>

#define D 64
#define EPS 2.5e-4f      // >= ~3x the fp16-split worst-case score-error bound
#define KSPLIT 2
#define CHUNK 64         // centroids per LDS tile
#define INVSC 4.8828125e-4f   // 2^-11, exact

typedef __attribute__((ext_vector_type(8))) _Float16 f16x8;
typedef __attribute__((ext_vector_type(4))) float f32x4;

// async global->LDS, 16 B per lane. LDS dst = wave-uniform base + lane*16.
static __device__ __forceinline__ void async16(const void* g, void* l) {
    __builtin_amdgcn_global_load_lds(
        (const __attribute__((address_space(1))) unsigned int*)((unsigned long long)g),
        (__attribute__((address_space(3))) unsigned int*)((unsigned int)(unsigned long long)l),
        16, 0, 0);
}

// prep: pre-swizzled fp16 hi/lo centroid images + c2 + zero counter.
// hi = fp16(c); lo = fp16((c - hi) * 2^11)  (scaling keeps lo normal-range).
__global__ void prep_kernel(const float* __restrict__ c, _Float16* __restrict__ chs,
                            _Float16* __restrict__ cls, float* __restrict__ c2,
                            int K, int* __restrict__ counter) {
    int t = blockIdx.x * blockDim.x + threadIdx.x;
    if (t == 0) *counter = 0;
    const int nfr = K * 8;
    if (t < nfr) {
        const int k = t >> 3, f = t & 7;
        const int ks = f >> 2, quad = f & 3;
        const int chunk = k >> 6, kc = (k >> 4) & 3, col = k & 15;
        const size_t off = (size_t)chunk * 4096 +
                           (size_t)(((kc * 2 + ks) * 64 + quad * 16 + col) * 8);
        const float* src = c + (size_t)k * D + f * 8;
        f16x8 h, l;
#pragma unroll
        for (int j = 0; j < 8; ++j) {
            float x = src[j];
            _Float16 hs = (_Float16)x;
            h[j] = hs;
            l[j] = (_Float16)((x - (float)hs) * 2048.f);
        }
        *(f16x8*)(chs + off) = h;
        *(f16x8*)(cls + off) = l;
    }
    if (t < K) {
        const float4* cp = (const float4*)(c + (size_t)t * D);
        float s = 0.f;
#pragma unroll
        for (int i = 0; i < D / 4; ++i) {
            float4 v = cp[i];
            s += v.x * v.x; s += v.y * v.y; s += v.z * v.z; s += v.w * v.w;
        }
        c2[t] = s;
    }
}

// Pass 1: fp16-hi/lo MFMA scan, B via double-buffered async LDS.
// __launch_bounds__(256,2): VGPR cap 256. (256,4) rounds r8-r11 showed the
// allocator squeezing to 64 regs and SPILLING (WRITE_SIZE 35-57 MB) instead
// of using the declared budget; occupancy is LDS-governed (32 KB -> 4/CU)
// so the reg headroom costs nothing.
__global__ __launch_bounds__(256, 2) void pass1_kernel(
    const float* __restrict__ action, const _Float16* __restrict__ chs,
    const _Float16* __restrict__ cls, const float* __restrict__ c2,
    float4* __restrict__ cand, int N, int K) {
    __shared__ _Float16 ldsbuf[2][2][4096];   // [dbuf][hi/lo][8 KB] = 32 KB

    const int tid  = threadIdx.x;
    const int wv   = tid >> 6;
    const int lane = tid & 63;
    const int col  = lane & 15;
    const int quad = lane >> 4;
    const int m0   = blockIdx.x * 128 + wv * 32;
    const int KC   = K / KSPLIT;
    const int k0   = blockIdx.y * KC;
    const int NC   = KC / CHUNK;           // 16
    const int ch0  = k0 >> 6;              // first chunk id

#define STAGE(cid_, buf_)                                                     \
    {                                                                         \
        const size_t gb = (size_t)(cid_) * 4096;                              \
        _Pragma("unroll") for (int r = 0; r < 2; ++r) {                       \
            const int el = (r * 256 + tid) * 8;                               \
            const int lb = (r * 256 + wv * 64) * 8;                           \
            async16(chs + gb + el, &ldsbuf[buf_][0][lb]);                     \
            async16(cls + gb + el, &ldsbuf[buf_][1][lb]);                     \
        }                                                                     \
    }

    STAGE(ch0, 0)   // chunk 0 in flight under A-fragment conversion

    // A fragments: a' = -2a -> fp16 hi + scaled fp16 lo, in registers once.
    f16x8 ah[2][2], al[2][2];
#pragma unroll
    for (int mi = 0; mi < 2; ++mi) {
        const float* arow = action + (size_t)(m0 + mi * 16 + col) * D;
#pragma unroll
        for (int ks = 0; ks < 2; ++ks) {
            const float* src = arow + ks * 32 + quad * 8;
            f16x8 h, l;
#pragma unroll
            for (int j = 0; j < 8; ++j) {
                float x = -2.f * src[j];
                _Float16 hs = (_Float16)x;
                h[j] = hs;
                l[j] = (_Float16)((x - (float)hs) * 2048.f);
            }
            ah[mi][ks] = h;
            al[mi][ks] = l;
        }
    }

    float b1[8], b2[8];
    int   bk[8];
#pragma unroll
    for (int e = 0; e < 8; ++e) {
        b1[e] = __builtin_inff(); b2[e] = __builtin_inff(); bk[e] = k0;
    }

#define FOLD(kk_)                                                             \
    _Pragma("unroll") for (int r = 0; r < 4; ++r) {                           \
        const int e = mi * 4 + r;                                             \
        const float s = fmaf(INVSC, acc2[r], acc1[r]);                        \
        b2[e] = __builtin_amdgcn_fmed3f(s, b1[e], b2[e]);                     \
        const bool better = s < b1[e];                                        \
        b1[e] = fminf(b1[e], s);                                              \
        bk[e] = better ? (kk_) : bk[e];                                       \
    }

#define KCBODY(kc_, cc_)                                                      \
    {                                                                         \
        f16x8 bh0 = *(const f16x8*)&ldsbuf[buf][0][(((kc_)*2+0)*64+lane)*8];  \
        f16x8 bh1 = *(const f16x8*)&ldsbuf[buf][0][(((kc_)*2+1)*64+lane)*8];  \
        f16x8 bl0 = *(const f16x8*)&ldsbuf[buf][1][(((kc_)*2+0)*64+lane)*8];  \
        f16x8 bl1 = *(const f16x8*)&ldsbuf[buf][1][(((kc_)*2+1)*64+lane)*8];  \
        const int k = kbase + (kc_)*16 + col;                                 \
        _Pragma("unroll") for (int mi = 0; mi < 2; ++mi) {                    \
            f32x4 acc1 = {cc_, cc_, cc_, cc_};                                \
            f32x4 acc2 = {0.f, 0.f, 0.f, 0.f};                                \
            acc2 = __builtin_amdgcn_mfma_f32_16x16x32_f16(al[mi][0], bh0, acc2, 0, 0, 0); \
            acc2 = __builtin_amdgcn_mfma_f32_16x16x32_f16(ah[mi][0], bl0, acc2, 0, 0, 0); \
            acc1 = __builtin_amdgcn_mfma_f32_16x16x32_f16(ah[mi][0], bh0, acc1, 0, 0, 0); \
            acc2 = __builtin_amdgcn_mfma_f32_16x16x32_f16(al[mi][1], bh1, acc2, 0, 0, 0); \
            acc2 = __builtin_amdgcn_mfma_f32_16x16x32_f16(ah[mi][1], bl1, acc2, 0, 0, 0); \
            acc1 = __builtin_amdgcn_mfma_f32_16x16x32_f16(ah[mi][1], bh1, acc1, 0, 0, 0); \
            FOLD(k)                                                           \
        }                                                                     \
    }

    for (int c = 0; c < NC; ++c) {
        const int buf = c & 1;
        __syncthreads();                    // chunk c resident in ldsbuf[buf]
        const int kbase = k0 + c * CHUNK;
        const float cc0 = c2[kbase + ((0 ^ wv) * 16) + col];
        const float cc1 = c2[kbase + ((1 ^ wv) * 16) + col];
        const float cc2 = c2[kbase + ((2 ^ wv) * 16) + col];
        const float cc3 = c2[kbase + ((3 ^ wv) * 16) + col];
        if (c + 1 < NC) STAGE(ch0 + c + 1, buf ^ 1)   // in flight under compute
        KCBODY((0 ^ wv), cc0)
        KCBODY((1 ^ wv), cc1)
        KCBODY((2 ^ wv), cc2)
        KCBODY((3 ^ wv), cc3)
    }
#undef KCBODY
#undef FOLD
#undef STAGE

    // cross-lane top-2 merge over the 16 centroid columns
#pragma unroll
    for (int off = 1; off < 16; off <<= 1) {
#pragma unroll
        for (int e = 0; e < 8; ++e) {
            float o1 = __shfl_xor(b1[e], off, 64);
            float o2 = __shfl_xor(b2[e], off, 64);
            int   ok = __shfl_xor(bk[e], off, 64);
            bool take = (o1 < b1[e]) || (o1 == b1[e] && ok < bk[e]);
            float nb2 = take ? fminf(b1[e], o2) : fminf(b2[e], o1);
            b1[e] = take ? o1 : b1[e];
            bk[e] = take ? ok : bk[e];
            b2[e] = nb2;
        }
    }

    if (col == 0) {
#pragma unroll
        for (int e = 0; e < 8; ++e) {
            const int mi = e >> 2, r = e & 3;
            const int p = m0 + mi * 16 + quad * 4 + r;
            cand[(size_t)blockIdx.y * N + p] =
                make_float4(b1[e], b2[e], (float)bk[e], 0.f);
        }
    }
}

// Merge split candidates, write bin, flag near-ties. (N threads.)
// Split0 owns lower k, so strict < keeps split0 on ties = numpy first-min.
__global__ void flag_kernel(const float4* __restrict__ cand,
                            float* __restrict__ out_bin,
                            int* __restrict__ counter, int* __restrict__ flags,
                            int N) {
    int n = blockIdx.x * blockDim.x + threadIdx.x;
    if (n >= N) return;
    float4 v0 = cand[n];
    float4 v1 = cand[(size_t)N + n];
    float b1, b2; int bk;
    if (v1.x < v0.x) { b1 = v1.x; bk = (int)v1.z; b2 = fminf(v0.x, v1.y); }
    else             { b1 = v0.x; bk = (int)v0.z; b2 = fminf(v1.x, v0.y); }
    out_bin[n] = (float)bk;
    if (b2 - b1 < EPS) {
        int idx = atomicAdd(counter, 1);
        flags[idx] = n;
    }
}

// Residuals in exact fp32, one float4 per thread (N*16 threads = 4096 blocks;
// r6-r11's fused per-point version ran at 1 block/CU and was the hidden
// ~80 us tail). Flagged points overwritten by exact_kernel afterwards.
__global__ void res_kernel(const float* __restrict__ action,
                           const float* __restrict__ centroids,
                           const float* __restrict__ out_bin,
                           float* __restrict__ out_res, int N) {
    int idx = blockIdx.x * blockDim.x + threadIdx.x;  // over N*16 float4s
    if (idx >= N * 16) return;
    int n = idx >> 4, j = idx & 15;
    int bk = (int)out_bin[n];
    float4 av = ((const float4*)action)[idx];
    float4 cv = ((const float4*)centroids)[bk * 16 + j];
    ((float4*)out_res)[idx] =
        make_float4(av.x - cv.x, av.y - cv.y, av.z - cv.z, av.w - cv.w);
}

// Exact fp32 rescan for flagged points. Block-per-point grid-stride,
// 4 interleaved dot accumulators for ILP. numpy first-min tie-break.
__global__ __launch_bounds__(256) void exact_kernel(
    const float* __restrict__ action, const float* __restrict__ centroids,
    const float* __restrict__ c2, const int* __restrict__ counter,
    const int* __restrict__ flags, float* __restrict__ out_bin,
    float* __restrict__ out_res, int K) {
    __shared__ float4 sa[D / 4];
    __shared__ float  swv[4];
    __shared__ int    swk[4];
    __shared__ int    s_bk;
    const int count = *counter;
    const int tid = threadIdx.x, lane = tid & 63, wid = tid >> 6;
    for (int i = blockIdx.x; i < count; i += gridDim.x) {
        const int n = flags[i];
        __syncthreads();
        if (tid < D / 4) sa[tid] = ((const float4*)(action + (size_t)n * D))[tid];
        __syncthreads();
        float best = __builtin_inff();
        int bbk = 0x7fffffff;
        for (int k = tid; k < K; k += 256) {
            const float4* cr = (const float4*)(centroids + (size_t)k * D);
            float d0 = 0.f, d1 = 0.f, d2 = 0.f, d3 = 0.f;
#pragma unroll
            for (int q = 0; q < 4; ++q) {
                float4 a0 = sa[q * 4 + 0], c0 = cr[q * 4 + 0];
                float4 a1 = sa[q * 4 + 1], c1 = cr[q * 4 + 1];
                float4 a2 = sa[q * 4 + 2], c2v = cr[q * 4 + 2];
                float4 a3 = sa[q * 4 + 3], c3 = cr[q * 4 + 3];
                d0 = fmaf(a0.x, c0.x, d0); d0 = fmaf(a0.y, c0.y, d0);
                d0 = fmaf(a0.z, c0.z, d0); d0 = fmaf(a0.w, c0.w, d0);
                d1 = fmaf(a1.x, c1.x, d1); d1 = fmaf(a1.y, c1.y, d1);
                d1 = fmaf(a1.z, c1.z, d1); d1 = fmaf(a1.w, c1.w, d1);
                d2 = fmaf(a2.x, c2v.x, d2); d2 = fmaf(a2.y, c2v.y, d2);
                d2 = fmaf(a2.z, c2v.z, d2); d2 = fmaf(a2.w, c2v.w, d2);
                d3 = fmaf(a3.x, c3.x, d3); d3 = fmaf(a3.y, c3.y, d3);
                d3 = fmaf(a3.z, c3.z, d3); d3 = fmaf(a3.w, c3.w, d3);
            }
            float dot = (d0 + d1) + (d2 + d3);
            float s = fmaf(-2.f, dot, c2[k]);
            if (s < best) { best = s; bbk = k; }  // ascending k: first-min
        }
#pragma unroll
        for (int off = 32; off > 0; off >>= 1) {
            float ov = __shfl_down(best, off, 64);
            int   ok = __shfl_down(bbk, off, 64);
            if (ov < best || (ov == best && ok < bbk)) { best = ov; bbk = ok; }
        }
        if (lane == 0) { swv[wid] = best; swk[wid] = bbk; }
        __syncthreads();
        if (tid == 0) {
            float bb = swv[0]; int bki = swk[0];
#pragma unroll
            for (int t = 1; t < 4; ++t)
                if (swv[t] < bb || (swv[t] == bb && swk[t] < bki)) {
                    bb = swv[t]; bki = swk[t];
                }
            out_bin[n] = (float)bki;
            s_bk = bki;
        }
        __syncthreads();
        if (tid < D / 4) {
            float4 a = sa[tid];
            float4 c = ((const float4*)(centroids + (size_t)s_bk * D))[tid];
            ((float4*)(out_res + (size_t)n * D))[tid] =
                make_float4(a.x - c.x, a.y - c.y, a.z - c.z, a.w - c.w);
        }
    }
}

extern "C" void kernel_launch(void* const* d_in, const int* in_sizes, int n_in,
                              void* d_out, int out_size, void* d_ws, size_t ws_size,
                              hipStream_t stream) {
    const float* action    = (const float*)d_in[0];  // [N, 64]
    const float* centroids = (const float*)d_in[1];  // [K, 64]
    const int N = in_sizes[0] / D;  // 65536
    const int K = in_sizes[1] / D;  // 2048

    float* out_bin = (float*)d_out;      // N floats: argmin index
    float* out_res = (float*)d_out + N;  // N*D residuals

    // ws layout (~2.9 MB)
    char* w = (char*)d_ws;
    float*     c2      = (float*)w;                       // 8 KB
    int*       counter = (int*)(w + 8192);                // 4 B (padded to 256)
    int*       flags   = (int*)(w + 8448);                // N*4 = 256 KB
    _Float16*  chs     = (_Float16*)(w + 8448 + 262144);  // K*D*2 = 256 KB (swizzled)
    _Float16*  cls     = chs + (size_t)K * D;             // 256 KB (swizzled)
    float4*    cand    = (float4*)(cls + (size_t)K * D);  // KSPLIT*N*16 = 2 MB

    prep_kernel<<<(K * 8 + 255) / 256, 256, 0, stream>>>(centroids, chs, cls,
                                                         c2, K, counter);
    dim3 g1(N / 128, KSPLIT);
    pass1_kernel<<<g1, 256, 0, stream>>>(action, chs, cls, c2, cand, N, K);
    flag_kernel<<<(N + 255) / 256, 256, 0, stream>>>(cand, out_bin, counter,
                                                     flags, N);
    res_kernel<<<(N * 16 + 255) / 256, 256, 0, stream>>>(action, centroids,
                                                         out_bin, out_res, N);
    exact_kernel<<<2048, 256, 0, stream>>>(action, centroids, c2, counter, flags,
                                           out_bin, out_res, K);
}

// Round 13
// 152.486 us; speedup vs baseline: 1.1480x; 1.0340x over previous
//
#include <hip/hip_runtime.h>

#define D 64
#define EPS 2.5e-4f      // >= ~3x the fp16-split worst-case score-error bound
#define CHUNK 64         // centroids per LDS tile
#define INVSC 4.8828125e-4f   // 2^-11, exact

typedef __attribute__((ext_vector_type(8))) _Float16 f16x8;
typedef __attribute__((ext_vector_type(4))) float f32x4;

// async global->LDS, 16 B per lane. LDS dst = wave-uniform base + lane*16.
static __device__ __forceinline__ void async16(const void* g, void* l) {
    __builtin_amdgcn_global_load_lds(
        (const __attribute__((address_space(1))) unsigned int*)((unsigned long long)g),
        (__attribute__((address_space(3))) unsigned int*)((unsigned int)(unsigned long long)l),
        16, 0, 0);
}

// prep: pre-swizzled fp16 hi/lo centroid images + c2 + zero counter.
// hi = fp16(c); lo = fp16((c - hi) * 2^11)  (scaling keeps lo normal-range).
__global__ void prep_kernel(const float* __restrict__ c, _Float16* __restrict__ chs,
                            _Float16* __restrict__ cls, float* __restrict__ c2,
                            int K, int* __restrict__ counter) {
    int t = blockIdx.x * blockDim.x + threadIdx.x;
    if (t == 0) *counter = 0;
    const int nfr = K * 8;
    if (t < nfr) {
        const int k = t >> 3, f = t & 7;
        const int ks = f >> 2, quad = f & 3;
        const int chunk = k >> 6, kc = (k >> 4) & 3, col = k & 15;
        const size_t off = (size_t)chunk * 4096 +
                           (size_t)(((kc * 2 + ks) * 64 + quad * 16 + col) * 8);
        const float* src = c + (size_t)k * D + f * 8;
        f16x8 h, l;
#pragma unroll
        for (int j = 0; j < 8; ++j) {
            float x = src[j];
            _Float16 hs = (_Float16)x;
            h[j] = hs;
            l[j] = (_Float16)((x - (float)hs) * 2048.f);
        }
        *(f16x8*)(chs + off) = h;
        *(f16x8*)(cls + off) = l;
    }
    if (t < K) {
        const float4* cp = (const float4*)(c + (size_t)t * D);
        float s = 0.f;
#pragma unroll
        for (int i = 0; i < D / 4; ++i) {
            float4 v = cp[i];
            s += v.x * v.x; s += v.y * v.y; s += v.z * v.z; s += v.w * v.w;
        }
        c2[t] = s;
    }
}

// Pass 1 (fully fused): fp16-hi/lo MFMA scan over ALL K + top-2 + bin write +
// near-tie flagging + exact fp32 residual for the block's 128 points.
// r12 ran this as 4 kernels with a 2 MB cand round-trip; the ~87 us tail
// collapses into ~10 us of inlined work here.
__global__ __launch_bounds__(256, 2) void pass1_kernel(
    const float* __restrict__ action, const _Float16* __restrict__ chs,
    const _Float16* __restrict__ cls, const float* __restrict__ c2,
    const float* __restrict__ centroids, float* __restrict__ out_bin,
    float* __restrict__ out_res, int* __restrict__ counter,
    int* __restrict__ flags, int N, int K) {
    __shared__ _Float16 ldsbuf[2][2][4096];   // [dbuf][hi/lo][8 KB] = 32 KB
    __shared__ int sbk[128];

    const int tid  = threadIdx.x;
    const int wv   = tid >> 6;
    const int lane = tid & 63;
    const int col  = lane & 15;
    const int quad = lane >> 4;
    const int mb   = blockIdx.x * 128;
    const int m0   = mb + wv * 32;
    const int NC   = K / CHUNK;            // 32

#define STAGE(cid_, buf_)                                                     \
    {                                                                         \
        const size_t gb = (size_t)(cid_) * 4096;                              \
        _Pragma("unroll") for (int r = 0; r < 2; ++r) {                       \
            const int el = (r * 256 + tid) * 8;                               \
            const int lb = (r * 256 + wv * 64) * 8;                           \
            async16(chs + gb + el, &ldsbuf[buf_][0][lb]);                     \
            async16(cls + gb + el, &ldsbuf[buf_][1][lb]);                     \
        }                                                                     \
    }

    STAGE(0, 0)   // chunk 0 in flight under A-fragment conversion

    // A fragments: a' = -2a -> fp16 hi + scaled fp16 lo, in registers once.
    f16x8 ah[2][2], al[2][2];
#pragma unroll
    for (int mi = 0; mi < 2; ++mi) {
        const float* arow = action + (size_t)(m0 + mi * 16 + col) * D;
#pragma unroll
        for (int ks = 0; ks < 2; ++ks) {
            const float* src = arow + ks * 32 + quad * 8;
            f16x8 h, l;
#pragma unroll
            for (int j = 0; j < 8; ++j) {
                float x = -2.f * src[j];
                _Float16 hs = (_Float16)x;
                h[j] = hs;
                l[j] = (_Float16)((x - (float)hs) * 2048.f);
            }
            ah[mi][ks] = h;
            al[mi][ks] = l;
        }
    }

    float b1[8], b2[8];
    int   bk[8];
#pragma unroll
    for (int e = 0; e < 8; ++e) {
        b1[e] = __builtin_inff(); b2[e] = __builtin_inff(); bk[e] = 0;
    }

#define FOLD(kk_)                                                             \
    _Pragma("unroll") for (int r = 0; r < 4; ++r) {                           \
        const int e = mi * 4 + r;                                             \
        const float s = fmaf(INVSC, acc2[r], acc1[r]);                        \
        b2[e] = __builtin_amdgcn_fmed3f(s, b1[e], b2[e]);                     \
        const bool better = s < b1[e];                                        \
        b1[e] = fminf(b1[e], s);                                              \
        bk[e] = better ? (kk_) : bk[e];                                       \
    }

#define KCBODY(kc_, cc_)                                                      \
    {                                                                         \
        f16x8 bh0 = *(const f16x8*)&ldsbuf[buf][0][(((kc_)*2+0)*64+lane)*8];  \
        f16x8 bh1 = *(const f16x8*)&ldsbuf[buf][0][(((kc_)*2+1)*64+lane)*8];  \
        f16x8 bl0 = *(const f16x8*)&ldsbuf[buf][1][(((kc_)*2+0)*64+lane)*8];  \
        f16x8 bl1 = *(const f16x8*)&ldsbuf[buf][1][(((kc_)*2+1)*64+lane)*8];  \
        const int k = kbase + (kc_)*16 + col;                                 \
        _Pragma("unroll") for (int mi = 0; mi < 2; ++mi) {                    \
            f32x4 acc1 = {cc_, cc_, cc_, cc_};                                \
            f32x4 acc2 = {0.f, 0.f, 0.f, 0.f};                                \
            acc2 = __builtin_amdgcn_mfma_f32_16x16x32_f16(al[mi][0], bh0, acc2, 0, 0, 0); \
            acc2 = __builtin_amdgcn_mfma_f32_16x16x32_f16(ah[mi][0], bl0, acc2, 0, 0, 0); \
            acc1 = __builtin_amdgcn_mfma_f32_16x16x32_f16(ah[mi][0], bh0, acc1, 0, 0, 0); \
            acc2 = __builtin_amdgcn_mfma_f32_16x16x32_f16(al[mi][1], bh1, acc2, 0, 0, 0); \
            acc2 = __builtin_amdgcn_mfma_f32_16x16x32_f16(ah[mi][1], bl1, acc2, 0, 0, 0); \
            acc1 = __builtin_amdgcn_mfma_f32_16x16x32_f16(ah[mi][1], bh1, acc1, 0, 0, 0); \
            FOLD(k)                                                           \
        }                                                                     \
    }

    for (int c = 0; c < NC; ++c) {
        const int buf = c & 1;
        __syncthreads();                    // chunk c resident in ldsbuf[buf]
        const int kbase = c * CHUNK;
        const float cc0 = c2[kbase + ((0 ^ wv) * 16) + col];
        const float cc1 = c2[kbase + ((1 ^ wv) * 16) + col];
        const float cc2 = c2[kbase + ((2 ^ wv) * 16) + col];
        const float cc3 = c2[kbase + ((3 ^ wv) * 16) + col];
        if (c + 1 < NC) STAGE(c + 1, buf ^ 1)   // in flight under compute
        KCBODY((0 ^ wv), cc0)
        KCBODY((1 ^ wv), cc1)
        KCBODY((2 ^ wv), cc2)
        KCBODY((3 ^ wv), cc3)
    }
#undef KCBODY
#undef FOLD
#undef STAGE

    // cross-lane top-2 merge over the 16 centroid columns
#pragma unroll
    for (int off = 1; off < 16; off <<= 1) {
#pragma unroll
        for (int e = 0; e < 8; ++e) {
            float o1 = __shfl_xor(b1[e], off, 64);
            float o2 = __shfl_xor(b2[e], off, 64);
            int   ok = __shfl_xor(bk[e], off, 64);
            bool take = (o1 < b1[e]) || (o1 == b1[e] && ok < bk[e]);
            float nb2 = take ? fminf(b1[e], o2) : fminf(b2[e], o1);
            b1[e] = take ? o1 : b1[e];
            bk[e] = take ? ok : bk[e];
            b2[e] = nb2;
        }
    }

    if (col == 0) {
#pragma unroll
        for (int e = 0; e < 8; ++e) {
            const int mi = e >> 2, r = e & 3;
            const int pl = wv * 32 + mi * 16 + quad * 4 + r;   // 0..127
            sbk[pl] = bk[e];
            out_bin[mb + pl] = (float)bk[e];
            if (b2[e] - b1[e] < EPS) {
                int idx = atomicAdd(counter, 1);
                flags[idx] = mb + pl;
            }
        }
    }
    __syncthreads();

    // exact fp32 residuals for the block's 128 points (2048 float4s).
    // 16 lanes per row -> 256 B contiguous centroid gather, coalesced I/O.
#pragma unroll
    for (int j = 0; j < 8; ++j) {
        const int idx = j * 256 + tid;
        const int row = idx >> 4, c4 = idx & 15;
        const int bki = sbk[row];
        float4 av = ((const float4*)(action + (size_t)(mb + row) * D))[c4];
        float4 cv = ((const float4*)centroids)[bki * 16 + c4];
        ((float4*)(out_res + (size_t)(mb + row) * D))[c4] =
            make_float4(av.x - cv.x, av.y - cv.y, av.z - cv.z, av.w - cv.w);
    }
}

// Exact fp32 rescan for flagged points. Block-per-point grid-stride,
// 4 interleaved dot accumulators for ILP. numpy first-min tie-break.
__global__ __launch_bounds__(256) void exact_kernel(
    const float* __restrict__ action, const float* __restrict__ centroids,
    const float* __restrict__ c2, const int* __restrict__ counter,
    const int* __restrict__ flags, float* __restrict__ out_bin,
    float* __restrict__ out_res, int K) {
    __shared__ float4 sa[D / 4];
    __shared__ float  swv[4];
    __shared__ int    swk[4];
    __shared__ int    s_bk;
    const int count = *counter;
    const int tid = threadIdx.x, lane = tid & 63, wid = tid >> 6;
    for (int i = blockIdx.x; i < count; i += gridDim.x) {
        const int n = flags[i];
        __syncthreads();
        if (tid < D / 4) sa[tid] = ((const float4*)(action + (size_t)n * D))[tid];
        __syncthreads();
        float best = __builtin_inff();
        int bbk = 0x7fffffff;
        for (int k = tid; k < K; k += 256) {
            const float4* cr = (const float4*)(centroids + (size_t)k * D);
            float d0 = 0.f, d1 = 0.f, d2 = 0.f, d3 = 0.f;
#pragma unroll
            for (int q = 0; q < 4; ++q) {
                float4 a0 = sa[q * 4 + 0], c0 = cr[q * 4 + 0];
                float4 a1 = sa[q * 4 + 1], c1 = cr[q * 4 + 1];
                float4 a2 = sa[q * 4 + 2], c2v = cr[q * 4 + 2];
                float4 a3 = sa[q * 4 + 3], c3 = cr[q * 4 + 3];
                d0 = fmaf(a0.x, c0.x, d0); d0 = fmaf(a0.y, c0.y, d0);
                d0 = fmaf(a0.z, c0.z, d0); d0 = fmaf(a0.w, c0.w, d0);
                d1 = fmaf(a1.x, c1.x, d1); d1 = fmaf(a1.y, c1.y, d1);
                d1 = fmaf(a1.z, c1.z, d1); d1 = fmaf(a1.w, c1.w, d1);
                d2 = fmaf(a2.x, c2v.x, d2); d2 = fmaf(a2.y, c2v.y, d2);
                d2 = fmaf(a2.z, c2v.z, d2); d2 = fmaf(a2.w, c2v.w, d2);
                d3 = fmaf(a3.x, c3.x, d3); d3 = fmaf(a3.y, c3.y, d3);
                d3 = fmaf(a3.z, c3.z, d3); d3 = fmaf(a3.w, c3.w, d3);
            }
            float dot = (d0 + d1) + (d2 + d3);
            float s = fmaf(-2.f, dot, c2[k]);
            if (s < best) { best = s; bbk = k; }  // ascending k: first-min
        }
#pragma unroll
        for (int off = 32; off > 0; off >>= 1) {
            float ov = __shfl_down(best, off, 64);
            int   ok = __shfl_down(bbk, off, 64);
            if (ov < best || (ov == best && ok < bbk)) { best = ov; bbk = ok; }
        }
        if (lane == 0) { swv[wid] = best; swk[wid] = bbk; }
        __syncthreads();
        if (tid == 0) {
            float bb = swv[0]; int bki = swk[0];
#pragma unroll
            for (int t = 1; t < 4; ++t)
                if (swv[t] < bb || (swv[t] == bb && swk[t] < bki)) {
                    bb = swv[t]; bki = swk[t];
                }
            out_bin[n] = (float)bki;
            s_bk = bki;
        }
        __syncthreads();
        if (tid < D / 4) {
            float4 a = sa[tid];
            float4 c = ((const float4*)(centroids + (size_t)s_bk * D))[tid];
            ((float4*)(out_res + (size_t)n * D))[tid] =
                make_float4(a.x - c.x, a.y - c.y, a.z - c.z, a.w - c.w);
        }
    }
}

extern "C" void kernel_launch(void* const* d_in, const int* in_sizes, int n_in,
                              void* d_out, int out_size, void* d_ws, size_t ws_size,
                              hipStream_t stream) {
    const float* action    = (const float*)d_in[0];  // [N, 64]
    const float* centroids = (const float*)d_in[1];  // [K, 64]
    const int N = in_sizes[0] / D;  // 65536
    const int K = in_sizes[1] / D;  // 2048

    float* out_bin = (float*)d_out;      // N floats: argmin index
    float* out_res = (float*)d_out + N;  // N*D residuals

    // ws layout (~0.8 MB)
    char* w = (char*)d_ws;
    float*     c2      = (float*)w;                       // 8 KB
    int*       counter = (int*)(w + 8192);                // 4 B (padded to 256)
    int*       flags   = (int*)(w + 8448);                // N*4 = 256 KB
    _Float16*  chs     = (_Float16*)(w + 8448 + 262144);  // K*D*2 = 256 KB (swizzled)
    _Float16*  cls     = chs + (size_t)K * D;             // 256 KB (swizzled)

    prep_kernel<<<(K * 8 + 255) / 256, 256, 0, stream>>>(centroids, chs, cls,
                                                         c2, K, counter);
    pass1_kernel<<<N / 128, 256, 0, stream>>>(action, chs, cls, c2, centroids,
                                              out_bin, out_res, counter, flags,
                                              N, K);
    exact_kernel<<<256, 256, 0, stream>>>(action, centroids, c2, counter, flags,
                                          out_bin, out_res, K);
}